// Round 5
// baseline (236.655 us; speedup 1.0000x reference)
//
#include <hip/hip_runtime.h>
#include <hip/hip_cooperative_groups.h>
#include <hip/hip_fp16.h>
#include <math.h>

namespace cg = cooperative_groups;

#define DIM   512
#define NBLK  128
#define NTHR  1024
#define NROW  4              // batch rows per block (128*4 = 512)
#define KP    256            // packed k-pairs
#define NKS   8              // k-slices
#define KPT   32             // kp per thread (KP/NKS)

typedef _Float16 h2 __attribute__((ext_vector_type(2)));

#if __has_builtin(__builtin_amdgcn_fdot2)
__device__ __forceinline__ float dot2f(unsigned a, unsigned b, float c){
  return __builtin_amdgcn_fdot2(__builtin_bit_cast(h2, a), __builtin_bit_cast(h2, b), c, false);
}
#else
__device__ __forceinline__ float dot2f(unsigned au, unsigned bu, float c){
  h2 a = __builtin_bit_cast(h2, au), b = __builtin_bit_cast(h2, bu);
  return fmaf((float)a[0], (float)b[0], fmaf((float)a[1], (float)b[1], c));
}
#endif

// ---- RKF56 coefficients ----
constexpr float cA21 = 0.25f;
constexpr float cA31 = (float)(3.0/32.0),     cA32 = (float)(9.0/32.0);
constexpr float cA41 = (float)(1932.0/2197.0),cA42 = (float)(-7200.0/2197.0), cA43 = (float)(7296.0/2197.0);
constexpr float cA51 = (float)(439.0/216.0),  cA52 = -8.0f,                   cA53 = (float)(3680.0/513.0), cA54 = (float)(-845.0/4104.0);
constexpr float cA61 = (float)(-8.0/27.0),    cA62 = 2.0f,                    cA63 = (float)(-3544.0/2565.0), cA64 = (float)(1859.0/4104.0), cA65 = (float)(-11.0/40.0);
constexpr float cB1 = (float)(16.0/135.0), cB3 = (float)(6656.0/12825.0), cB4 = (float)(28561.0/56430.0), cB5 = (float)(-9.0/50.0), cB6 = (float)(2.0/55.0);
constexpr float cC1 = (float)(25.0/216.0), cC3 = (float)(1408.0/2565.0),  cC4 = (float)(2197.0/4104.0),  cC5 = -0.2f;

constexpr float TOLf = 0.01f, MIN_DTf = 0.1f, DT0f = 0.1f, MAXTf = 50.0f, VELTOLf = 0.05f;
constexpr float INVD = 1.0f/512.0f;

__device__ __forceinline__ unsigned packh(float a, float b){
  unsigned short lo = __half_as_ushort(__float2half(a));   // RNE
  unsigned short hi = __half_as_ushort(__float2half(b));
  return (unsigned)lo | ((unsigned)hi << 16);
}

// scalar grid barrier: one slot per use (zeroed by host memset), no bulk L2 flush
__device__ __forceinline__ void gbar(unsigned* ctr, int tid){
  __syncthreads();
  if (tid == 0){
    __hip_atomic_fetch_add(ctr, 1u, __ATOMIC_RELEASE, __HIP_MEMORY_SCOPE_AGENT);
    unsigned v;
    do {
      __builtin_amdgcn_s_sleep(2);
      v = __hip_atomic_load(ctr, __ATOMIC_RELAXED, __HIP_MEMORY_SCOPE_AGENT);
    } while (v < NBLK);
    (void)__hip_atomic_load(ctr, __ATOMIC_ACQUIRE, __HIP_MEMORY_SCOPE_AGENT);
  }
  __syncthreads();
}

// acc[r][c] += sum_j dot2(w_c[j], y_r[j])  for one 4-kp chunk
#define RC(r,c,wv,yv) \
  acc[r][c] = dot2f(wv.x, yv.x, acc[r][c]); \
  acc[r][c] = dot2f(wv.y, yv.y, acc[r][c]); \
  acc[r][c] = dot2f(wv.z, yv.z, acc[r][c]); \
  acc[r][c] = dot2f(wv.w, yv.w, acc[r][c]);

__global__ void __launch_bounds__(NTHR, 1)
hop_kernel(const float* __restrict__ x0, const float* __restrict__ W,
           const float* __restrict__ bvec, float* __restrict__ out,
           unsigned char* __restrict__ ws)
{
  cg::grid_group grid = cg::this_grid();

  unsigned*           bar  = (unsigned*)ws;                    // 96 slots
  unsigned*           errs = (unsigned*)(ws + 384);            // errs[32]
  unsigned long long* vels = (unsigned long long*)(ws + 512);  // vels[32]
  unsigned*           Wq   = (unsigned*)(ws + 4096);           // [kp/4][c][kp&3] f16x2, 512 KB
  unsigned*           WTq  = Wq + KP*DIM;                      // transposed, 512 KB

  const int tid  = threadIdx.x;
  const int b    = blockIdx.x;
  const int wid  = tid >> 6;
  const int lane = tid & 63;

  // matmul layout: k-slice x column-group (wave-uniform k-slice)
  const int ks = tid >> 7;             // 0..7
  const int cg = tid & 127;            // 0..127 -> cols 4cg..4cg+3
  // pointwise layout: one row, one column-pair
  const int pr   = tid >> 8;           // 0..3
  const int pc   = tid & 255;          // col-pair index (== kp it owns)
  const int colA = pc << 1;
  const int grow = b*NROW + pr;        // global batch row

  __shared__ __align__(16) unsigned pkY[NROW*KP];  // [row][kp] f16x2, 4 KB
  __shared__ __align__(16) unsigned pkS[NROW*KP];  // [row][kp] f16x2, 4 KB
  __shared__ __align__(16) float sPart[NKS*NROW*DIM];  // 64 KB partials
  __shared__ float red[32];
  __shared__ float bcast[4];

  // ---- one-time: W -> interleaved packed f16 (normal + transposed) ----
  {
    int e  = b*NTHR + tid;                    // [0, 131072)
    int kp = e >> 9, c = e & 511;
    size_t qi = (size_t)(kp >> 2)*2048 + (size_t)c*4 + (kp & 3);
    Wq[qi] = packh(W[(size_t)(2*kp)*DIM + c], W[(size_t)(2*kp+1)*DIM + c]);
    float2 wt = *reinterpret_cast<const float2*>(W + (size_t)c*DIM + 2*kp);
    WTq[qi] = packh(wt.x, wt.y);
  }

  // per-thread persistent state: 2 elements of one batch row (pointwise layout)
  float x[2], bv[2];
  { float2 xx = *reinterpret_cast<const float2*>(x0 + (size_t)grow*DIM + colA);
    x[0]=xx.x; x[1]=xx.y; }
  { float2 b2 = *reinterpret_cast<const float2*>(bvec + colA);
    bv[0]=b2.x; bv[1]=b2.y; }

  grid.sync();   // publish Wq/WTq across XCDs (once)

  float t = 0.f, dt = DT0f;
  float k1[2],k2[2],k3[2],k4[2],k5[2],xhi[2],yreg[2];

  // C=4 columns x 4 rows x 32 kp; store partials to sPart[ks][r][4cg..4cg+3]
  auto mm_store = [&](const unsigned* __restrict__ Wp, const unsigned* __restrict__ pk){
    float acc[4][4];
    #pragma unroll
    for (int r = 0; r < 4; ++r)
      #pragma unroll
      for (int c = 0; c < 4; ++c) acc[r][c] = 0.f;
    const unsigned* wp = Wp + (size_t)(ks*8)*2048 + (size_t)cg*16;
    const int kb = ks*KPT;
    #pragma unroll
    for (int ch = 0; ch < 8; ++ch){
      const int kpc = kb + ch*4;
      uint4 w0 = *reinterpret_cast<const uint4*>(wp + 0);
      uint4 w1 = *reinterpret_cast<const uint4*>(wp + 4);
      uint4 w2 = *reinterpret_cast<const uint4*>(wp + 8);
      uint4 w3 = *reinterpret_cast<const uint4*>(wp + 12);
      wp += 2048;
      uint4 y0 = *reinterpret_cast<const uint4*>(&pk[0*KP + kpc]);  // broadcast
      uint4 y1 = *reinterpret_cast<const uint4*>(&pk[1*KP + kpc]);
      uint4 y2 = *reinterpret_cast<const uint4*>(&pk[2*KP + kpc]);
      uint4 y3 = *reinterpret_cast<const uint4*>(&pk[3*KP + kpc]);
      RC(0,0,w0,y0) RC(0,1,w1,y0) RC(0,2,w2,y0) RC(0,3,w3,y0)
      RC(1,0,w0,y1) RC(1,1,w1,y1) RC(1,2,w2,y1) RC(1,3,w3,y1)
      RC(2,0,w0,y2) RC(2,1,w1,y2) RC(2,2,w2,y2) RC(2,3,w3,y2)
      RC(3,0,w0,y3) RC(3,1,w1,y3) RC(3,2,w2,y3) RC(3,3,w3,y3)
    }
    #pragma unroll
    for (int r = 0; r < 4; ++r){
      float4 v; v.x=acc[r][0]; v.y=acc[r][1]; v.z=acc[r][2]; v.w=acc[r][3];
      *reinterpret_cast<float4*>(&sPart[(ks*NROW + r)*DIM + cg*4]) = v;
    }
  };

  auto comb = [&](float g[2]){   // sum the NKS k-slice partials (pointwise layout)
    float s0 = 0.f, s1 = 0.f;
    #pragma unroll
    for (int kk = 0; kk < NKS; ++kk){
      float2 p = *reinterpret_cast<const float2*>(&sPart[(kk*NROW + pr)*DIM + colA]);
      s0 += p.x; s1 += p.y;
    }
    g[0] = s0; g[1] = s1;
  };

  auto set_y = [&](float y0, float y1){
    yreg[0] = y0; yreg[1] = y1;
    pkY[pr*KP + pc] = packh(y0, y1);
    __syncthreads();
  };
  auto run_fwd = [&](){
    mm_store(Wq, pkY);
    __syncthreads();
    float g[2]; comb(g);
    float th0 = tanhf(g[0] + bv[0]);
    float th1 = tanhf(g[1] + bv[1]);
    pkS[pr*KP + pc] = packh(1.f - th0*th0, 1.f - th1*th1);
    __syncthreads();
  };
  auto run_bwd = [&](float ko[2]){
    mm_store(WTq, pkS);
    __syncthreads();
    float g[2]; comb(g);
    ko[0] = -(2.f*yreg[0] + g[0]) * INVD;
    ko[1] = -(2.f*yreg[1] + g[1]) * INVD;
  };

  // ---- prologue: k1 = pvf(x0) ----
  set_y(x[0], x[1]);
  run_fwd(); run_bwd(k1);

  for (int iter = 0; iter < 32; ++iter){
    // ---- stages 2..5 ----
    set_y(x[0]+dt*(cA21*k1[0]), x[1]+dt*(cA21*k1[1]));
    run_fwd(); run_bwd(k2);
    set_y(x[0]+dt*(cA31*k1[0]+cA32*k2[0]), x[1]+dt*(cA31*k1[1]+cA32*k2[1]));
    run_fwd(); run_bwd(k3);
    set_y(x[0]+dt*(cA41*k1[0]+cA42*k2[0]+cA43*k3[0]),
          x[1]+dt*(cA41*k1[1]+cA42*k2[1]+cA43*k3[1]));
    run_fwd(); run_bwd(k4);
    set_y(x[0]+dt*(cA51*k1[0]+cA52*k2[0]+cA53*k3[0]+cA54*k4[0]),
          x[1]+dt*(cA51*k1[1]+cA52*k2[1]+cA53*k3[1]+cA54*k4[1]));
    run_fwd(); run_bwd(k5);

    // ---- stage 6 fused: k6 / x_hi / x_lo / err ----
    set_y(x[0]+dt*(cA61*k1[0]+cA62*k2[0]+cA63*k3[0]+cA64*k4[0]+cA65*k5[0]),
          x[1]+dt*(cA61*k1[1]+cA62*k2[1]+cA63*k3[1]+cA64*k4[1]+cA65*k5[1]));
    run_fwd();
    mm_store(WTq, pkS);
    __syncthreads();
    {
      float g[2]; comb(g);
      float emax = 0.f;
      #pragma unroll
      for (int i = 0; i < 2; ++i){
        float k6 = -(2.f*yreg[i] + g[i]) * INVD;
        float hi = x[i] + dt*(cB1*k1[i] + cB3*k3[i] + cB4*k4[i] + cB5*k5[i] + cB6*k6);
        float lo = x[i] + dt*(cC1*k1[i] + cC3*k3[i] + cC4*k4[i] + cC5*k5[i]);
        xhi[i] = hi;
        emax = fmaxf(emax, fabsf(hi - lo));
      }
      #pragma unroll
      for (int s = 32; s > 0; s >>= 1) emax = fmaxf(emax, __shfl_xor(emax, s, 64));
      if (lane == 0) red[wid] = emax;
      __syncthreads();
      if (tid == 0){
        float m = red[0];
        #pragma unroll
        for (int wv = 1; wv < 16; ++wv) m = fmaxf(m, red[wv]);
        atomicMax(&errs[iter], __float_as_uint(m));
      }
    }

    gbar(&bar[2*iter], tid);                        // grid barrier #1
    if (tid == 0)
      bcast[0] = __uint_as_float(__hip_atomic_load(&errs[iter], __ATOMIC_RELAXED, __HIP_MEMORY_SCOPE_AGENT));
    __syncthreads();
    const float err = bcast[0];
    const bool accept = (err < TOLf) || (dt <= MIN_DTf);
    if (accept){ x[0]=xhi[0]; x[1]=xhi[1]; }

    // ---- stop condition: k1_next = pvf(x2); vel from it ----
    set_y(x[0], x[1]);
    run_fwd(); run_bwd(k1);          // doubles as next iteration's k1
    {
      float vmax = fmaxf(fabsf(k1[0]), fabsf(k1[1]));
      #pragma unroll
      for (int s = 32; s > 0; s >>= 1) vmax = fmaxf(vmax, __shfl_xor(vmax, s, 64));
      if (lane == 0) red[wid] = vmax;               // 4 waves per row
      __syncthreads();
      if (tid == 0){
        double rsum = 0.0;
        #pragma unroll
        for (int rr = 0; rr < NROW; ++rr){
          float rm = fmaxf(fmaxf(red[4*rr], red[4*rr+1]), fmaxf(red[4*rr+2], red[4*rr+3]));
          rsum += (double)rm;
        }
        unsigned long long fx = (unsigned long long)(rsum * 4294967296.0);
        atomicAdd(&vels[iter], fx);
      }
    }

    gbar(&bar[2*iter+1], tid);                      // grid barrier #2
    if (tid == 0){
      unsigned long long sv = __hip_atomic_load(&vels[iter], __ATOMIC_RELAXED, __HIP_MEMORY_SCOPE_AGENT);
      float vel = (float)((double)sv * (1.0/4294967296.0) / 512.0);
      float t2  = accept ? (t + dt) : t;
      float factor = 0.9f * powf(TOLf / (err + 1e-12f), 0.2f);
      factor = fminf(fmaxf(factor, 0.2f), 2.0f);
      float dtn = fmaxf(dt * factor, MIN_DTf);
      bcast[0] = t2; bcast[1] = dtn;
      bcast[2] = ((t2 > MAXTf) || (vel < VELTOLf)) ? 1.f : 0.f;
    }
    __syncthreads();
    t = bcast[0]; dt = bcast[1];
    if (bcast[2] != 0.f) break;                     // uniform across grid
  }

  float2 o; o.x = x[0]; o.y = x[1];
  *reinterpret_cast<float2*>(out + (size_t)grow*DIM + colA) = o;
}

extern "C" void kernel_launch(void* const* d_in, const int* in_sizes, int n_in,
                              void* d_out, int out_size, void* d_ws, size_t ws_size,
                              hipStream_t stream)
{
  const float* x0 = (const float*)d_in[0];
  const float* W  = (const float*)d_in[1];
  const float* bv = (const float*)d_in[2];
  float* out = (float*)d_out;
  unsigned char* ws = (unsigned char*)d_ws;

  hipMemsetAsync(ws, 0, 4096, stream);   // barrier slots + errs + vels

  void* args[] = { (void*)&x0, (void*)&W, (void*)&bv, (void*)&out, (void*)&ws };
  (void)in_sizes; (void)n_in; (void)out_size; (void)ws_size;
  hipLaunchCooperativeKernel((void*)hop_kernel, dim3(NBLK), dim3(NTHR), args, 0, stream);
}

// Round 6
// 192.304 us; speedup vs baseline: 1.2306x; 1.2306x over previous
//
#include <hip/hip_runtime.h>
#include <hip/hip_cooperative_groups.h>
#include <hip/hip_fp16.h>
#include <math.h>

namespace cg = cooperative_groups;

#define DIM   512
#define NBLK  128
#define NTHR  1024
#define NROW  4              // batch rows per block (128*4 = 512)
#define KP    256            // packed k-pairs
#define NKS   8              // k-slices
#define KPT   32             // kp per thread (KP/NKS)

typedef _Float16 h2 __attribute__((ext_vector_type(2)));

#if __has_builtin(__builtin_amdgcn_fdot2)
__device__ __forceinline__ float dot2f(unsigned a, unsigned b, float c){
  return __builtin_amdgcn_fdot2(__builtin_bit_cast(h2, a), __builtin_bit_cast(h2, b), c, false);
}
#else
__device__ __forceinline__ float dot2f(unsigned au, unsigned bu, float c){
  h2 a = __builtin_bit_cast(h2, au), b = __builtin_bit_cast(h2, bu);
  return fmaf((float)a[0], (float)b[0], fmaf((float)a[1], (float)b[1], c));
}
#endif

// ---- RKF56 coefficients ----
constexpr float cA21 = 0.25f;
constexpr float cA31 = (float)(3.0/32.0),     cA32 = (float)(9.0/32.0);
constexpr float cA41 = (float)(1932.0/2197.0),cA42 = (float)(-7200.0/2197.0), cA43 = (float)(7296.0/2197.0);
constexpr float cA51 = (float)(439.0/216.0),  cA52 = -8.0f,                   cA53 = (float)(3680.0/513.0), cA54 = (float)(-845.0/4104.0);
constexpr float cA61 = (float)(-8.0/27.0),    cA62 = 2.0f,                    cA63 = (float)(-3544.0/2565.0), cA64 = (float)(1859.0/4104.0), cA65 = (float)(-11.0/40.0);
constexpr float cB1 = (float)(16.0/135.0), cB3 = (float)(6656.0/12825.0), cB4 = (float)(28561.0/56430.0), cB5 = (float)(-9.0/50.0), cB6 = (float)(2.0/55.0);
constexpr float cC1 = (float)(25.0/216.0), cC3 = (float)(1408.0/2565.0),  cC4 = (float)(2197.0/4104.0),  cC5 = -0.2f;

constexpr float TOLf = 0.01f, MIN_DTf = 0.1f, DT0f = 0.1f, MAXTf = 50.0f, VELTOLf = 0.05f;
constexpr float INVD = 1.0f/512.0f;

__device__ __forceinline__ unsigned packh(float a, float b){
  unsigned short lo = __half_as_ushort(__float2half(a));   // RNE
  unsigned short hi = __half_as_ushort(__float2half(b));
  return (unsigned)lo | ((unsigned)hi << 16);
}

// acc[r][j] += dot2 over one 4-kp chunk
#define RC(r,j,wv,yv) \
  acc[r][j] = dot2f(wv.x, yv.x, acc[r][j]); \
  acc[r][j] = dot2f(wv.y, yv.y, acc[r][j]); \
  acc[r][j] = dot2f(wv.z, yv.z, acc[r][j]); \
  acc[r][j] = dot2f(wv.w, yv.w, acc[r][j]);

__global__ void __launch_bounds__(NTHR, 1)
hop_kernel(const float* __restrict__ x0, const float* __restrict__ W,
           const float* __restrict__ bvec, float* __restrict__ out,
           unsigned char* __restrict__ ws)
{
  cg::grid_group grid = cg::this_grid();

  unsigned*           bar  = (unsigned*)ws;                    // 64 slots
  unsigned*           errs = (unsigned*)(ws + 384);            // errs[32]
  unsigned long long* vels = (unsigned long long*)(ws + 512);  // vels[32]
  unsigned*           Wq   = (unsigned*)(ws + 4096);           // [kp/4][c][kp&3] f16x2, 512 KB
  unsigned*           WTq  = Wq + KP*DIM;                      // transposed, 512 KB

  const int tid  = threadIdx.x;
  const int b    = blockIdx.x;
  const int wid  = tid >> 6;
  const int lane = tid & 63;

  // matmul layout: k-slice x column-group; thread owns cols cg+128j (coalesced)
  const int ks = tid >> 7;             // 0..7
  const int cgi = tid & 127;           // 0..127
  // pointwise layout: one row, one column-pair
  const int pr   = tid >> 8;           // 0..3
  const int pc   = tid & 255;          // col-pair index (== kp it owns)
  const int colA = pc << 1;
  const int grow = b*NROW + pr;        // global batch row

  __shared__ __align__(16) unsigned pkY[NROW*KP];      // [row][kp] f16x2, 4 KB
  __shared__ __align__(16) unsigned pkS[NROW*KP];      // [row][kp] f16x2, 4 KB
  __shared__ __align__(16) float sPart[NKS*NROW*DIM];  // 64 KB partials
  __shared__ float red[32];
  __shared__ float bcast[4];

  // ---- one-time: W -> interleaved packed f16 (normal + transposed) ----
  {
    int e  = b*NTHR + tid;                    // [0, 131072)
    int kp = e >> 9, c = e & 511;
    size_t qi = (size_t)(kp >> 2)*2048 + (size_t)c*4 + (kp & 3);
    Wq[qi] = packh(W[(size_t)(2*kp)*DIM + c], W[(size_t)(2*kp+1)*DIM + c]);
    float2 wt = *reinterpret_cast<const float2*>(W + (size_t)c*DIM + 2*kp);
    WTq[qi] = packh(wt.x, wt.y);
  }

  // per-thread persistent state: 2 elements of one batch row (pointwise layout)
  float x[2], bv[2];
  { float2 xx = *reinterpret_cast<const float2*>(x0 + (size_t)grow*DIM + colA);
    x[0]=xx.x; x[1]=xx.y; }
  { float2 b2 = *reinterpret_cast<const float2*>(bvec + colA);
    bv[0]=b2.x; bv[1]=b2.y; }

  grid.sync();   // publish Wq/WTq across XCDs (once; only fence in the kernel)

  float t = 0.f, dt = DT0f;
  float k1[2],k2[2],k3[2],k4[2],k5[2],xhi[2],yreg[2];

  // 4 rows x 4 cols (stride 128) x 32 kp; partials to sPart[ks][r][col]
  auto mm_store = [&](const unsigned* __restrict__ Wp, const unsigned* __restrict__ pk){
    float acc[4][4];
    #pragma unroll
    for (int r = 0; r < 4; ++r)
      #pragma unroll
      for (int j = 0; j < 4; ++j) acc[r][j] = 0.f;
    const unsigned* wp = Wp + (size_t)(ks*8)*2048 + (size_t)cgi*4;
    const int kb = ks*KPT;
    #pragma unroll
    for (int ch = 0; ch < 8; ++ch){
      const int kpc = kb + ch*4;
      uint4 w0 = *reinterpret_cast<const uint4*>(wp +    0);   // col cgi      (lane-contig 16B)
      uint4 w1 = *reinterpret_cast<const uint4*>(wp +  512);   // col cgi+128
      uint4 w2 = *reinterpret_cast<const uint4*>(wp + 1024);   // col cgi+256
      uint4 w3 = *reinterpret_cast<const uint4*>(wp + 1536);   // col cgi+384
      wp += 2048;
      uint4 y0 = *reinterpret_cast<const uint4*>(&pk[0*KP + kpc]);  // broadcast
      uint4 y1 = *reinterpret_cast<const uint4*>(&pk[1*KP + kpc]);
      uint4 y2 = *reinterpret_cast<const uint4*>(&pk[2*KP + kpc]);
      uint4 y3 = *reinterpret_cast<const uint4*>(&pk[3*KP + kpc]);
      RC(0,0,w0,y0) RC(0,1,w1,y0) RC(0,2,w2,y0) RC(0,3,w3,y0)
      RC(1,0,w0,y1) RC(1,1,w1,y1) RC(1,2,w2,y1) RC(1,3,w3,y1)
      RC(2,0,w0,y2) RC(2,1,w1,y2) RC(2,2,w2,y2) RC(2,3,w3,y2)
      RC(3,0,w0,y3) RC(3,1,w1,y3) RC(3,2,w2,y3) RC(3,3,w3,y3)
    }
    #pragma unroll
    for (int r = 0; r < 4; ++r)
      #pragma unroll
      for (int j = 0; j < 4; ++j)
        sPart[(ks*NROW + r)*DIM + cgi + 128*j] = acc[r][j];
  };

  auto comb = [&](float g[2]){   // sum the NKS k-slice partials (pointwise layout)
    float s0 = 0.f, s1 = 0.f;
    #pragma unroll
    for (int kk = 0; kk < NKS; ++kk){
      float2 p = *reinterpret_cast<const float2*>(&sPart[(kk*NROW + pr)*DIM + colA]);
      s0 += p.x; s1 += p.y;
    }
    g[0] = s0; g[1] = s1;
  };

  auto set_y = [&](float y0, float y1){
    yreg[0] = y0; yreg[1] = y1;
    pkY[pr*KP + pc] = packh(y0, y1);
    __syncthreads();
  };
  auto run_fwd = [&](){
    mm_store(Wq, pkY);
    __syncthreads();
    float g[2]; comb(g);
    float th0 = tanhf(g[0] + bv[0]);
    float th1 = tanhf(g[1] + bv[1]);
    pkS[pr*KP + pc] = packh(1.f - th0*th0, 1.f - th1*th1);
    __syncthreads();
  };
  auto run_bwd = [&](float ko[2]){
    mm_store(WTq, pkS);
    __syncthreads();
    float g[2]; comb(g);
    ko[0] = -(2.f*yreg[0] + g[0]) * INVD;
    ko[1] = -(2.f*yreg[1] + g[1]) * INVD;
  };

  // spin until counter reaches NBLK (relaxed; atomics are coherent at device scope)
  auto spin_bar = [&](unsigned* ctr){
    unsigned v;
    do {
      __builtin_amdgcn_s_sleep(2);
      v = __hip_atomic_load(ctr, __ATOMIC_RELAXED, __HIP_MEMORY_SCOPE_AGENT);
    } while (v < NBLK);
  };

  // ---- prologue: k1 = pvf(x0) ----
  set_y(x[0], x[1]);
  run_fwd(); run_bwd(k1);

  for (int iter = 0; iter < 32; ++iter){
    // ---- stages 2..5 ----
    set_y(x[0]+dt*(cA21*k1[0]), x[1]+dt*(cA21*k1[1]));
    run_fwd(); run_bwd(k2);
    set_y(x[0]+dt*(cA31*k1[0]+cA32*k2[0]), x[1]+dt*(cA31*k1[1]+cA32*k2[1]));
    run_fwd(); run_bwd(k3);
    set_y(x[0]+dt*(cA41*k1[0]+cA42*k2[0]+cA43*k3[0]),
          x[1]+dt*(cA41*k1[1]+cA42*k2[1]+cA43*k3[1]));
    run_fwd(); run_bwd(k4);
    set_y(x[0]+dt*(cA51*k1[0]+cA52*k2[0]+cA53*k3[0]+cA54*k4[0]),
          x[1]+dt*(cA51*k1[1]+cA52*k2[1]+cA53*k3[1]+cA54*k4[1]));
    run_fwd(); run_bwd(k5);

    // ---- stage 6 fused: k6 / x_hi / x_lo / err ----
    set_y(x[0]+dt*(cA61*k1[0]+cA62*k2[0]+cA63*k3[0]+cA64*k4[0]+cA65*k5[0]),
          x[1]+dt*(cA61*k1[1]+cA62*k2[1]+cA63*k3[1]+cA64*k4[1]+cA65*k5[1]));
    run_fwd();
    mm_store(WTq, pkS);
    __syncthreads();
    {
      float g[2]; comb(g);
      float emax = 0.f;
      #pragma unroll
      for (int i = 0; i < 2; ++i){
        float k6 = -(2.f*yreg[i] + g[i]) * INVD;
        float hi = x[i] + dt*(cB1*k1[i] + cB3*k3[i] + cB4*k4[i] + cB5*k5[i] + cB6*k6);
        float lo = x[i] + dt*(cC1*k1[i] + cC3*k3[i] + cC4*k4[i] + cC5*k5[i]);
        xhi[i] = hi;
        emax = fmaxf(emax, fabsf(hi - lo));
      }
      #pragma unroll
      for (int s = 32; s > 0; s >>= 1) emax = fmaxf(emax, __shfl_xor(emax, s, 64));
      if (lane == 0) red[wid] = emax;
      __syncthreads();
      if (tid == 0){
        float m = red[0];
        #pragma unroll
        for (int wv = 1; wv < 16; ++wv) m = fmaxf(m, red[wv]);
        // relaxed RMW publish; arrival add data-depends on the RMW result
        unsigned old = __hip_atomic_fetch_max(&errs[iter], __float_as_uint(m),
                                              __ATOMIC_RELAXED, __HIP_MEMORY_SCOPE_AGENT);
        if (old != 0xFFFFFFFFu)   // always true; forces wait on the err RMW first
          __hip_atomic_fetch_add(&bar[2*iter], 1u, __ATOMIC_RELAXED, __HIP_MEMORY_SCOPE_AGENT);
      }
    }

    __syncthreads();
    if (tid == 0){
      spin_bar(&bar[2*iter]);
      unsigned eb = __hip_atomic_fetch_max(&errs[iter], 0u,
                                           __ATOMIC_RELAXED, __HIP_MEMORY_SCOPE_AGENT);
      bcast[0] = __uint_as_float(eb);
    }
    __syncthreads();
    const float err = bcast[0];
    const bool accept = (err < TOLf) || (dt <= MIN_DTf);
    if (accept){ x[0]=xhi[0]; x[1]=xhi[1]; }

    // ---- stop condition: k1_next = pvf(x2); vel from it ----
    set_y(x[0], x[1]);
    run_fwd(); run_bwd(k1);          // doubles as next iteration's k1
    {
      float vmax = fmaxf(fabsf(k1[0]), fabsf(k1[1]));
      #pragma unroll
      for (int s = 32; s > 0; s >>= 1) vmax = fmaxf(vmax, __shfl_xor(vmax, s, 64));
      if (lane == 0) red[wid] = vmax;               // 4 waves per row
      __syncthreads();
      if (tid == 0){
        double rsum = 0.0;
        #pragma unroll
        for (int rr = 0; rr < NROW; ++rr){
          float rm = fmaxf(fmaxf(red[4*rr], red[4*rr+1]), fmaxf(red[4*rr+2], red[4*rr+3]));
          rsum += (double)rm;
        }
        unsigned long long fx = (unsigned long long)(rsum * 4294967296.0);
        unsigned long long vo = __hip_atomic_fetch_add(&vels[iter], fx,
                                    __ATOMIC_RELAXED, __HIP_MEMORY_SCOPE_AGENT);
        if (vo != ~0ull)            // always true; forces wait on the vel RMW first
          __hip_atomic_fetch_add(&bar[2*iter+1], 1u, __ATOMIC_RELAXED, __HIP_MEMORY_SCOPE_AGENT);
      }
    }

    __syncthreads();
    if (tid == 0){
      spin_bar(&bar[2*iter+1]);
      unsigned long long sv = __hip_atomic_fetch_add(&vels[iter], 0ull,
                                  __ATOMIC_RELAXED, __HIP_MEMORY_SCOPE_AGENT);
      float vel = (float)((double)sv * (1.0/4294967296.0) / 512.0);
      float t2  = accept ? (t + dt) : t;
      float factor = 0.9f * powf(TOLf / (err + 1e-12f), 0.2f);
      factor = fminf(fmaxf(factor, 0.2f), 2.0f);
      float dtn = fmaxf(dt * factor, MIN_DTf);
      bcast[0] = t2; bcast[1] = dtn;
      bcast[2] = ((t2 > MAXTf) || (vel < VELTOLf)) ? 1.f : 0.f;
    }
    __syncthreads();
    t = bcast[0]; dt = bcast[1];
    if (bcast[2] != 0.f) break;                     // uniform across grid
  }

  float2 o; o.x = x[0]; o.y = x[1];
  *reinterpret_cast<float2*>(out + (size_t)grow*DIM + colA) = o;
}

extern "C" void kernel_launch(void* const* d_in, const int* in_sizes, int n_in,
                              void* d_out, int out_size, void* d_ws, size_t ws_size,
                              hipStream_t stream)
{
  const float* x0 = (const float*)d_in[0];
  const float* W  = (const float*)d_in[1];
  const float* bv = (const float*)d_in[2];
  float* out = (float*)d_out;
  unsigned char* ws = (unsigned char*)d_ws;

  hipMemsetAsync(ws, 0, 4096, stream);   // barrier slots + errs + vels

  void* args[] = { (void*)&x0, (void*)&W, (void*)&bv, (void*)&out, (void*)&ws };
  (void)in_sizes; (void)n_in; (void)out_size; (void)ws_size;
  hipLaunchCooperativeKernel((void*)hop_kernel, dim3(NBLK), dim3(NTHR), args, 0, stream);
}